// Round 3
// baseline (2678.254 us; speedup 1.0000x reference)
//
#include <hip/hip_runtime.h>
#include <hip/hip_bf16.h>
#include <math.h>

#define L_  6
#define D_  384
#define NH_ 6
#define HD_ 64
#define HF_ 768
#define V_  4096
#define B_  4
#define T_  2048
#define BT_ (B_*T_)

typedef unsigned short u16;
typedef __attribute__((ext_vector_type(8))) short short8;
typedef __attribute__((ext_vector_type(4))) float f32x4;

__device__ __forceinline__ float bf2f(u16 u){
  union { unsigned int i; float f; } c; c.i = ((unsigned int)u)<<16; return c.f;
}
__device__ __forceinline__ u16 f2bf(float f){
  union { float f; unsigned int i; } c; c.f = f;
  unsigned int x = c.i;
  x += 0x7fffu + ((x>>16)&1u);
  return (u16)(x>>16);
}
__device__ __forceinline__ f32x4 mfma16(short8 a, short8 b, f32x4 c){
  return __builtin_amdgcn_mfma_f32_16x16x32_bf16(a,b,c,0,0,0);
}

// ---------------- embedding gather: h_f32[t,d] = emb[x[t],d] ----------------
__global__ void embed_kernel(const int* __restrict__ x, const float* __restrict__ emb,
                             float* __restrict__ h){
  const int idx = blockIdx.x*256 + threadIdx.x;
  if(idx >= BT_*D_) return;
  const int t = idx / D_;
  const int d = idx - t*D_;
  h[idx] = emb[(size_t)x[t]*D_ + d];
}

// -------- weight transpose + cast: dst_bf16[b][n][k] = src_f32[b][k][n] -----
__global__ void transpose_kernel(const float* __restrict__ src, u16* __restrict__ dst,
                                 int K, int N, size_t dstBatchStride){
  const int bz = blockIdx.y;
  const int idx = blockIdx.x*256 + threadIdx.x;
  if(idx >= K*N) return;
  const int kk = idx / N, nn = idx - kk*N;
  dst[(size_t)bz*dstBatchStride + (size_t)nn*K + kk] = f2bf(src[(size_t)bz*K*N + idx]);
}

// ---------------- rmsnorm: one wave per row of 384 (f32 in, bf16 out) -------
__global__ __launch_bounds__(256) void rms_kernel(const float* __restrict__ h,
                                                  const float* __restrict__ w,
                                                  u16* __restrict__ out){
  const int wave = threadIdx.x>>6, lane = threadIdx.x&63;
  const size_t row = (size_t)blockIdx.x*4 + wave;
  const float* hr = h + row*D_;
  float v[6]; float ss = 0.f;
  #pragma unroll
  for(int i=0;i<6;i++){ v[i] = hr[lane + i*64]; ss += v[i]*v[i]; }
  #pragma unroll
  for(int o=1;o<64;o<<=1) ss += __shfl_xor(ss, o);
  const float rn = rsqrtf(ss*(1.f/D_) + 1e-6f);
  u16* orow = out + row*D_;
  #pragma unroll
  for(int i=0;i<6;i++) orow[lane+i*64] = f2bf(v[i]*rn*w[lane+i*64]);
}

// ---------------- f32 -> f32 copy (mid output) ----------------
__global__ void copy_kernel(const float* __restrict__ src, float* __restrict__ dst, int n){
  const int i = blockIdx.x*256 + threadIdx.x;
  if(i < n) dst[i] = src[i];
}

// ---------------- MFMA GEMM: C[M,N] = A[M,K] @ Wt[N,K]^T ----------------
// 64x64 tile per block (4 waves, 16 rows each). MODE: 0=plain f32 out (fout),
// 1=bias+gelu bf16 out, 2=f32 residual += (+optional f32 bias), 3=QKV split.
template<int MODE, int K>
__global__ __launch_bounds__(256) void gemm_kernel(
    const u16* __restrict__ A, const u16* __restrict__ Wt, int N,
    const float* __restrict__ bias, u16* __restrict__ out, float* __restrict__ fout,
    u16* __restrict__ qo, u16* __restrict__ ko, u16* __restrict__ vo)
{
  const int wave = threadIdx.x>>6, lane = threadIdx.x&63;
  const int l16 = lane&15, quad = lane>>4;
  const int tn = blockIdx.x, tm = blockIdx.y;
  const int r0 = tm*64 + wave*16;
  const u16* ap = A  + (size_t)(r0 + l16)*K + quad*8;
  const u16* bp = Wt + (size_t)(tn*64 + l16)*K + quad*8;
  f32x4 acc[4];
  #pragma unroll
  for(int c=0;c<4;c++){ acc[c][0]=0.f; acc[c][1]=0.f; acc[c][2]=0.f; acc[c][3]=0.f; }
  #pragma unroll 4
  for(int k0=0;k0<K;k0+=32){
    short8 af = *(const short8*)(ap + k0);
    #pragma unroll
    for(int c=0;c<4;c++){
      short8 bf = *(const short8*)(bp + (size_t)c*(16*K) + k0);
      acc[c] = mfma16(af, bf, acc[c]);
    }
  }
  #pragma unroll
  for(int c=0;c<4;c++){
    const int col = tn*64 + c*16 + l16;
    #pragma unroll
    for(int r=0;r<4;r++){
      const int row = r0 + quad*4 + r;
      float v = acc[c][r];
      if(MODE==0){
        fout[(size_t)row*N + col] = v;
      } else if(MODE==1){
        v += bias[col];
        v = 0.5f*v*(1.f + erff(v*0.70710678118f));
        out[(size_t)row*N + col] = f2bf(v);
      } else if(MODE==2){
        if(bias) v += bias[col];
        fout[(size_t)row*N + col] += v;
      } else {
        if(col < D_)        qo[(size_t)row*D_ + col]        = f2bf(v);
        else if(col < 2*D_) ko[(size_t)row*D_ + (col-D_)]   = f2bf(v);
        else {
          const int cv = col - 2*D_;
          const int hh = cv>>6, dd = cv&63;
          const int bb = row>>11, tt = row&(T_-1);
          vo[(((size_t)(bb*NH_+hh))*HD_ + dd)*T_ + tt] = f2bf(v);
        }
      }
    }
  }
}

// ---------------- causal flash attention ----------------
// grid (T/64, B*NH), block 256. Each wave: 16 q rows, online softmax over k.
// q,k: [B*T, 384] (per-head slice), vt: [B,NH,HD,T] transposed. ao: [B*T,384].
__global__ __launch_bounds__(256) void flash_kernel(const u16* __restrict__ q,
    const u16* __restrict__ k, const u16* __restrict__ vt, u16* __restrict__ ao){
  __shared__ __align__(16) u16 Pb[4][16][72];  // per-wave P tile, +8 pad
  const int wave = threadIdx.x>>6, lane = threadIdx.x&63;
  const int l16 = lane&15, quad = lane>>4;
  const int bh = blockIdx.y, b = bh/NH_, h = bh - b*NH_;
  const int qw = blockIdx.x*64 + wave*16;

  const u16* qp = q  + ((size_t)(b*T_ + qw + l16))*D_ + h*HD_ + quad*8;
  const u16* kp = k  + ((size_t)(b*T_))*D_ + h*HD_ + quad*8;
  const u16* vp = vt + ((size_t)(b*NH_ + h))*HD_*T_ + quad*8;

  short8 qf0 = *(const short8*)(qp);
  short8 qf1 = *(const short8*)(qp + 32);

  float m[4], l[4];
  f32x4 o[4];
  #pragma unroll
  for(int r=0;r<4;r++){ m[r] = -1e30f; l[r] = 0.f; }
  #pragma unroll
  for(int c=0;c<4;c++){ o[c][0]=0.f; o[c][1]=0.f; o[c][2]=0.f; o[c][3]=0.f; }

  const int nkt = qw/64 + 1;   // causal: k-tiles with kb <= qw
  for(int kt=0; kt<nkt; kt++){
    const int kb = kt*64;
    float s[4][4];
    #pragma unroll
    for(int c=0;c<4;c++){
      const u16* kr = kp + (size_t)(kb + c*16 + l16)*D_;
      short8 kf0 = *(const short8*)(kr);
      short8 kf1 = *(const short8*)(kr + 32);
      f32x4 sa = {0.f,0.f,0.f,0.f};
      sa = mfma16(qf0, kf0, sa);
      sa = mfma16(qf1, kf1, sa);
      const int kpos = kb + c*16 + l16;
      #pragma unroll
      for(int r=0;r<4;r++)
        s[c][r] = (kpos <= qw + quad*4 + r) ? sa[r]*0.125f : -1e30f;
    }
    #pragma unroll
    for(int r=0;r<4;r++){
      float tm = fmaxf(fmaxf(s[0][r],s[1][r]), fmaxf(s[2][r],s[3][r]));
      tm = fmaxf(tm, __shfl_xor(tm,1));
      tm = fmaxf(tm, __shfl_xor(tm,2));
      tm = fmaxf(tm, __shfl_xor(tm,4));
      tm = fmaxf(tm, __shfl_xor(tm,8));
      const float mn = fmaxf(m[r], tm);
      const float al = __expf(m[r] - mn);
      float rs = 0.f;
      #pragma unroll
      for(int c=0;c<4;c++){
        const float p = __expf(s[c][r] - mn);
        rs += p;
        Pb[wave][quad*4 + r][c*16 + l16] = f2bf(p);
      }
      rs += __shfl_xor(rs,1); rs += __shfl_xor(rs,2);
      rs += __shfl_xor(rs,4); rs += __shfl_xor(rs,8);
      l[r] = l[r]*al + rs;
      m[r] = mn;
      #pragma unroll
      for(int c=0;c<4;c++) o[c][r] *= al;
    }
    short8 pf0 = *(const short8*)(&Pb[wave][l16][quad*8]);
    short8 pf1 = *(const short8*)(&Pb[wave][l16][32 + quad*8]);
    #pragma unroll
    for(int c=0;c<4;c++){
      const u16* vr = vp + (size_t)(c*16 + l16)*T_ + kb;
      short8 vf0 = *(const short8*)(vr);
      short8 vf1 = *(const short8*)(vr + 32);
      o[c] = mfma16(pf0, vf0, o[c]);
      o[c] = mfma16(pf1, vf1, o[c]);
    }
  }
  #pragma unroll
  for(int c=0;c<4;c++){
    #pragma unroll
    for(int r=0;r<4;r++){
      const size_t row = (size_t)(b*T_ + qw + quad*4 + r);
      ao[row*D_ + h*HD_ + c*16 + l16] = f2bf(o[c][r] / l[r]);
    }
  }
}

extern "C" void kernel_launch(void* const* d_in, const int* in_sizes, int n_in,
                              void* d_out, int out_size, void* d_ws, size_t ws_size,
                              hipStream_t stream) {
  const int*   x    = (const int*)d_in[0];
  const float* emb  = (const float*)d_in[1];
  const float* wq   = (const float*)d_in[2];
  const float* wk   = (const float*)d_in[3];
  const float* wv   = (const float*)d_in[4];
  const float* wo   = (const float*)d_in[5];
  const float* ln1  = (const float*)d_in[6];
  const float* ln2  = (const float*)d_in[7];
  const float* w1   = (const float*)d_in[8];
  const float* b1   = (const float*)d_in[9];
  const float* w2   = (const float*)d_in[10];
  const float* b2   = (const float*)d_in[11];
  const float* lnf  = (const float*)d_in[12];
  const float* head = (const float*)d_in[13];
  float* out = (float*)d_out;             // reference output dtype is float32

  char* ws = (char*)d_ws; size_t off = 0;
  auto alloc = [&](size_t bytes)->void* {
    void* p = ws + off; off += (bytes + 255) & ~(size_t)255; return p;
  };
  float* hbuf  = (float*)alloc((size_t)BT_*D_*4);
  u16* xn    = (u16*)alloc((size_t)BT_*D_*2);
  u16* qb    = (u16*)alloc((size_t)BT_*D_*2);
  u16* kb    = (u16*)alloc((size_t)BT_*D_*2);
  u16* vtb   = (u16*)alloc((size_t)BT_*D_*2);
  u16* aob   = (u16*)alloc((size_t)BT_*D_*2);
  u16* midb  = (u16*)alloc((size_t)BT_*HF_*2);
  u16* qkvt  = (u16*)alloc((size_t)L_*3*D_*D_*2);
  u16* wot   = (u16*)alloc((size_t)L_*D_*D_*2);
  u16* w1t   = (u16*)alloc((size_t)L_*HF_*D_*2);
  u16* w2t   = (u16*)alloc((size_t)L_*D_*HF_*2);
  u16* headt = (u16*)alloc((size_t)V_*D_*2);

  const dim3 blk(256);
  // weight transposes (Wt[N,K] bf16 layout for contiguous B-fragments)
  const int ndd = (D_*D_ + 255)/256;
  transpose_kernel<<<dim3(ndd, L_), blk, 0, stream>>>(wq, qkvt,           D_, D_, (size_t)3*D_*D_);
  transpose_kernel<<<dim3(ndd, L_), blk, 0, stream>>>(wk, qkvt + D_*D_,   D_, D_, (size_t)3*D_*D_);
  transpose_kernel<<<dim3(ndd, L_), blk, 0, stream>>>(wv, qkvt + 2*D_*D_, D_, D_, (size_t)3*D_*D_);
  transpose_kernel<<<dim3(ndd, L_), blk, 0, stream>>>(wo, wot,            D_, D_, (size_t)D_*D_);
  const int ndh = (D_*HF_ + 255)/256;
  transpose_kernel<<<dim3(ndh, L_), blk, 0, stream>>>(w1, w1t, D_, HF_, (size_t)HF_*D_);
  transpose_kernel<<<dim3(ndh, L_), blk, 0, stream>>>(w2, w2t, HF_, D_, (size_t)D_*HF_);
  transpose_kernel<<<dim3((D_*V_ + 255)/256, 1), blk, 0, stream>>>(head, headt, D_, V_, 0);

  embed_kernel<<<(BT_*D_ + 255)/256, blk, 0, stream>>>(x, emb, hbuf);

  for(int li=0; li<L_; li++){
    rms_kernel<<<BT_/4, blk, 0, stream>>>(hbuf, ln1 + li*D_, xn);
    gemm_kernel<3,D_><<<dim3(3*D_/64, BT_/64), blk, 0, stream>>>(
        xn, qkvt + (size_t)li*3*D_*D_, 3*D_, nullptr, nullptr, nullptr, qb, kb, vtb);
    flash_kernel<<<dim3(T_/64, B_*NH_), blk, 0, stream>>>(qb, kb, vtb, aob);
    gemm_kernel<2,D_><<<dim3(D_/64, BT_/64), blk, 0, stream>>>(
        aob, wot + (size_t)li*D_*D_, D_, nullptr, nullptr, hbuf, nullptr, nullptr, nullptr);
    rms_kernel<<<BT_/4, blk, 0, stream>>>(hbuf, ln2 + li*D_, xn);
    gemm_kernel<1,D_><<<dim3(HF_/64, BT_/64), blk, 0, stream>>>(
        xn, w1t + (size_t)li*HF_*D_, HF_, b1 + li*HF_, midb, nullptr, nullptr, nullptr, nullptr);
    gemm_kernel<2,HF_><<<dim3(D_/64, BT_/64), blk, 0, stream>>>(
        midb, w2t + (size_t)li*D_*HF_, D_, b2 + li*D_, nullptr, hbuf, nullptr, nullptr, nullptr);
    if(li == 2)
      copy_kernel<<<(BT_*D_ + 255)/256, blk, 0, stream>>>(hbuf, out + (size_t)BT_*V_, BT_*D_);
  }
  rms_kernel<<<BT_/4, blk, 0, stream>>>(hbuf, lnf, xn);
  gemm_kernel<0,D_><<<dim3(V_/64, BT_/64), blk, 0, stream>>>(
      xn, headt, V_, nullptr, nullptr, out, nullptr, nullptr, nullptr);
}

// Round 4
// 1532.476 us; speedup vs baseline: 1.7477x; 1.7477x over previous
//
#include <hip/hip_runtime.h>
#include <hip/hip_bf16.h>
#include <math.h>

#define L_  6
#define D_  384
#define NH_ 6
#define HD_ 64
#define HF_ 768
#define V_  4096
#define B_  4
#define T_  2048
#define BT_ (B_*T_)

typedef unsigned short u16;
typedef __attribute__((ext_vector_type(8))) short short8;
typedef __attribute__((ext_vector_type(4))) float f32x4;

__device__ __forceinline__ float bf2f(u16 u){
  union { unsigned int i; float f; } c; c.i = ((unsigned int)u)<<16; return c.f;
}
__device__ __forceinline__ u16 f2bf(float f){
  union { float f; unsigned int i; } c; c.f = f;
  unsigned int x = c.i;
  x += 0x7fffu + ((x>>16)&1u);
  return (u16)(x>>16);
}
__device__ __forceinline__ f32x4 mfma16(short8 a, short8 b, f32x4 c){
  return __builtin_amdgcn_mfma_f32_16x16x32_bf16(a,b,c,0,0,0);
}
// async global->LDS, 16B per lane, LDS dest = base + lane*16 (wave-uniform base)
#define GLD16(gp, lp) __builtin_amdgcn_global_load_lds( \
    (const __attribute__((address_space(1))) void*)(gp), \
    (__attribute__((address_space(3))) void*)(lp), 16, 0, 0)

// ---------------- embedding gather ----------------
__global__ void embed_kernel(const int* __restrict__ x, const float* __restrict__ emb,
                             float* __restrict__ h){
  const int idx = blockIdx.x*256 + threadIdx.x;
  if(idx >= BT_*D_) return;
  const int t = idx / D_;
  const int d = idx - t*D_;
  h[idx] = emb[(size_t)x[t]*D_ + d];
}

// ---- coalesced LDS-tiled weight transpose+cast: dst[b][n][k]=bf16(src[b][k][n])
__global__ __launch_bounds__(256) void wtrans_kernel(const float* __restrict__ src,
    u16* __restrict__ dst, int K, int N, size_t srcBatch, size_t dstBatch){
  __shared__ float tile[32][33];
  src += (size_t)blockIdx.z*srcBatch;
  dst += (size_t)blockIdx.z*dstBatch;
  const int tx = threadIdx.x&31, ty = threadIdx.x>>5;
  const int n0 = blockIdx.x*32, k0 = blockIdx.y*32;
  #pragma unroll
  for(int j=0;j<4;j++)
    tile[ty+j*8][tx] = src[(size_t)(k0+ty+j*8)*N + n0+tx];
  __syncthreads();
  #pragma unroll
  for(int j=0;j<4;j++)
    dst[(size_t)(n0+ty+j*8)*K + k0+tx] = f2bf(tile[tx][ty+j*8]);
}

// ---------------- rmsnorm: one wave per row of 384 ----------------
__global__ __launch_bounds__(256) void rms_kernel(const float* __restrict__ h,
                                                  const float* __restrict__ w,
                                                  u16* __restrict__ out){
  const int wave = threadIdx.x>>6, lane = threadIdx.x&63;
  const size_t row = (size_t)blockIdx.x*4 + wave;
  const float* hr = h + row*D_;
  float v[6]; float ss = 0.f;
  #pragma unroll
  for(int i=0;i<6;i++){ v[i] = hr[lane + i*64]; ss += v[i]*v[i]; }
  #pragma unroll
  for(int o=1;o<64;o<<=1) ss += __shfl_xor(ss, o);
  const float rn = rsqrtf(ss*(1.f/D_) + 1e-6f);
  u16* orow = out + row*D_;
  #pragma unroll
  for(int i=0;i<6;i++) orow[lane+i*64] = f2bf(v[i]*rn*w[lane+i*64]);
}

// ---------------- f32 -> f32 copy (mid output) ----------------
__global__ void copy_kernel(const float* __restrict__ src, float* __restrict__ dst, int n){
  const int i = blockIdx.x*256 + threadIdx.x;
  if(i < n) dst[i] = src[i];
}

// ---------------- MFMA GEMM: C[M,N] = A[M,K] @ Wt[N,K]^T ----------------
// 128x128 tile/block, 4 waves (2x2 of 64x64), BK=64, global_load_lds staging
// into XOR-swizzled LDS. MODE: 0=f32 out, 1=bias+gelu bf16, 2=f32 resid +=,
// 3=QKV split (v transposed to [B,NH,HD,T]).
template<int MODE, int K>
__global__ __launch_bounds__(256) void gemm_kernel(
    const u16* __restrict__ A, const u16* __restrict__ Wt, int N,
    const float* __restrict__ bias, u16* __restrict__ out, float* __restrict__ fout,
    u16* __restrict__ qo, u16* __restrict__ ko, u16* __restrict__ vo)
{
  __shared__ u16 As[128*64];
  __shared__ u16 Bs[128*64];
  const int w = threadIdx.x>>6, lane = threadIdx.x&63;
  const int l16 = lane&15, quad = lane>>4;
  const int wm = w&1, wn = w>>1;
  const int r0 = blockIdx.y*128, n0 = blockIdx.x*128;
  const int mst = lane>>3;                 // row within 1KB wave-chunk (8 rows)
  const int cst = (lane&7) ^ (lane>>3);    // swizzled global 16B-chunk index

  f32x4 acc[4][4];
  #pragma unroll
  for(int mi=0;mi<4;mi++)
    #pragma unroll
    for(int ni=0;ni<4;ni++){ acc[mi][ni][0]=0.f; acc[mi][ni][1]=0.f; acc[mi][ni][2]=0.f; acc[mi][ni][3]=0.f; }

  for(int k0=0;k0<K;k0+=64){
    __syncthreads();
    #pragma unroll
    for(int i=0;i<4;i++){
      const int m = (w*4+i)*8 + mst;       // 0..127
      GLD16(A  + (size_t)(r0+m)*K + k0 + cst*8, As + (size_t)(w*4+i)*512);
      GLD16(Wt + (size_t)(n0+m)*K + k0 + cst*8, Bs + (size_t)(w*4+i)*512);
    }
    asm volatile("s_waitcnt vmcnt(0)" ::: "memory");
    __syncthreads();
    #pragma unroll
    for(int ks=0;ks<2;ks++){
      short8 av[4], bv[4];
      #pragma unroll
      for(int mi=0;mi<4;mi++){
        const int m = wm*64 + mi*16 + l16;
        av[mi] = *(const short8*)&As[m*64 + (((ks*4+quad)^(l16&7))*8)];
      }
      #pragma unroll
      for(int ni=0;ni<4;ni++){
        const int n = wn*64 + ni*16 + l16;
        bv[ni] = *(const short8*)&Bs[n*64 + (((ks*4+quad)^(l16&7))*8)];
      }
      #pragma unroll
      for(int mi=0;mi<4;mi++)
        #pragma unroll
        for(int ni=0;ni<4;ni++)
          acc[mi][ni] = mfma16(av[mi], bv[ni], acc[mi][ni]);
    }
  }

  #pragma unroll
  for(int mi=0;mi<4;mi++){
    #pragma unroll
    for(int ni=0;ni<4;ni++){
      const int col = n0 + wn*64 + ni*16 + l16;
      #pragma unroll
      for(int r=0;r<4;r++){
        const int row = r0 + wm*64 + mi*16 + quad*4 + r;
        float v = acc[mi][ni][r];
        if(MODE==0){
          fout[(size_t)row*N + col] = v;
        } else if(MODE==1){
          v += bias[col];
          v = 0.5f*v*(1.f + erff(v*0.70710678118f));
          out[(size_t)row*N + col] = f2bf(v);
        } else if(MODE==2){
          if(bias) v += bias[col];
          fout[(size_t)row*N + col] += v;
        } else {
          if(col < D_)        qo[(size_t)row*D_ + col]      = f2bf(v);
          else if(col < 2*D_) ko[(size_t)row*D_ + (col-D_)] = f2bf(v);
          else {
            const int cv = col - 2*D_;
            const int hh = cv>>6, dd = cv&63;
            const int bb = row>>11, tt = row&(T_-1);
            vo[(((size_t)(bb*NH_+hh))*HD_ + dd)*T_ + tt] = f2bf(v);
          }
        }
      }
    }
  }
}

// ---------------- causal flash attention, block-shared K/V LDS tiles --------
// grid (T/64, B*NH), 4 waves; all waves share the same k-tile range.
__global__ __launch_bounds__(256) void flash_kernel(const u16* __restrict__ q,
    const u16* __restrict__ k, const u16* __restrict__ vt, u16* __restrict__ ao){
  __shared__ u16 Ks[64*64];
  __shared__ u16 Vs[64*64];
  __shared__ __align__(16) u16 Pb[4][16][72];
  const int w = threadIdx.x>>6, lane = threadIdx.x&63;
  const int l16 = lane&15, quad = lane>>4;
  const int bh = blockIdx.y, b = bh/NH_, h = bh - b*NH_;
  const int qw = blockIdx.x*64 + w*16;
  const int mst = lane>>3;
  const int cst = (lane&7) ^ (lane>>3);

  const u16* qp = q + ((size_t)(b*T_ + qw + l16))*D_ + h*HD_ + quad*8;
  short8 qf0 = *(const short8*)(qp);
  short8 qf1 = *(const short8*)(qp + 32);

  float m[4], l[4];
  f32x4 o[4];
  #pragma unroll
  for(int r=0;r<4;r++){ m[r] = -1e30f; l[r] = 0.f; }
  #pragma unroll
  for(int c=0;c<4;c++){ o[c][0]=0.f; o[c][1]=0.f; o[c][2]=0.f; o[c][3]=0.f; }

  const int nkt = blockIdx.x + 1;
  for(int kt=0; kt<nkt; kt++){
    const int kb = kt*64;
    __syncthreads();
    #pragma unroll
    for(int i=0;i<2;i++){
      const int rr = (w*2+i)*8 + mst;       // 0..63
      GLD16(k  + (size_t)(b*T_ + kb + rr)*D_ + h*HD_ + cst*8, Ks + (size_t)(w*2+i)*512);
      GLD16(vt + ((size_t)(b*NH_ + h)*HD_ + rr)*T_ + kb + cst*8, Vs + (size_t)(w*2+i)*512);
    }
    asm volatile("s_waitcnt vmcnt(0)" ::: "memory");
    __syncthreads();

    float s[4][4];
    #pragma unroll
    for(int c=0;c<4;c++){
      const int krow = c*16 + l16;
      short8 kf0 = *(const short8*)&Ks[krow*64 + ((quad^(l16&7))*8)];
      short8 kf1 = *(const short8*)&Ks[krow*64 + (((4+quad)^(l16&7))*8)];
      f32x4 sa = {0.f,0.f,0.f,0.f};
      sa = mfma16(qf0, kf0, sa);
      sa = mfma16(qf1, kf1, sa);
      #pragma unroll
      for(int r=0;r<4;r++) s[c][r] = sa[r]*0.125f;
    }
    if(kt == nkt-1){
      #pragma unroll
      for(int c=0;c<4;c++){
        const int kpos = kb + c*16 + l16;
        #pragma unroll
        for(int r=0;r<4;r++)
          if(kpos > qw + quad*4 + r) s[c][r] = -1e30f;
      }
    }
    #pragma unroll
    for(int r=0;r<4;r++){
      float tm = fmaxf(fmaxf(s[0][r],s[1][r]), fmaxf(s[2][r],s[3][r]));
      tm = fmaxf(tm, __shfl_xor(tm,1));
      tm = fmaxf(tm, __shfl_xor(tm,2));
      tm = fmaxf(tm, __shfl_xor(tm,4));
      tm = fmaxf(tm, __shfl_xor(tm,8));
      const float mn = fmaxf(m[r], tm);
      const float al = __expf(m[r] - mn);
      float rs = 0.f;
      #pragma unroll
      for(int c=0;c<4;c++){
        const float p = __expf(s[c][r] - mn);
        rs += p;
        Pb[w][quad*4 + r][c*16 + l16] = f2bf(p);
      }
      rs += __shfl_xor(rs,1); rs += __shfl_xor(rs,2);
      rs += __shfl_xor(rs,4); rs += __shfl_xor(rs,8);
      l[r] = l[r]*al + rs;
      m[r] = mn;
      #pragma unroll
      for(int c=0;c<4;c++) o[c][r] *= al;
    }
    short8 pf0 = *(const short8*)(&Pb[w][l16][quad*8]);
    short8 pf1 = *(const short8*)(&Pb[w][l16][32 + quad*8]);
    #pragma unroll
    for(int c=0;c<4;c++){
      const int vrow = c*16 + l16;     // d index
      short8 vf0 = *(const short8*)&Vs[vrow*64 + ((quad^(l16&7))*8)];
      short8 vf1 = *(const short8*)&Vs[vrow*64 + (((4+quad)^(l16&7))*8)];
      o[c] = mfma16(pf0, vf0, o[c]);
      o[c] = mfma16(pf1, vf1, o[c]);
    }
  }
  #pragma unroll
  for(int c=0;c<4;c++){
    #pragma unroll
    for(int r=0;r<4;r++){
      const size_t row = (size_t)(b*T_ + qw + quad*4 + r);
      ao[row*D_ + h*HD_ + c*16 + l16] = f2bf(o[c][r] / l[r]);
    }
  }
}

extern "C" void kernel_launch(void* const* d_in, const int* in_sizes, int n_in,
                              void* d_out, int out_size, void* d_ws, size_t ws_size,
                              hipStream_t stream) {
  const int*   x    = (const int*)d_in[0];
  const float* emb  = (const float*)d_in[1];
  const float* wq   = (const float*)d_in[2];
  const float* wk   = (const float*)d_in[3];
  const float* wv   = (const float*)d_in[4];
  const float* wo   = (const float*)d_in[5];
  const float* ln1  = (const float*)d_in[6];
  const float* ln2  = (const float*)d_in[7];
  const float* w1   = (const float*)d_in[8];
  const float* b1   = (const float*)d_in[9];
  const float* w2   = (const float*)d_in[10];
  const float* b2   = (const float*)d_in[11];
  const float* lnf  = (const float*)d_in[12];
  const float* head = (const float*)d_in[13];
  float* out = (float*)d_out;

  char* ws = (char*)d_ws; size_t off = 0;
  auto alloc = [&](size_t bytes)->void* {
    void* p = ws + off; off += (bytes + 255) & ~(size_t)255; return p;
  };
  float* hbuf  = (float*)alloc((size_t)BT_*D_*4);
  u16* xn    = (u16*)alloc((size_t)BT_*D_*2);
  u16* qb    = (u16*)alloc((size_t)BT_*D_*2);
  u16* kb    = (u16*)alloc((size_t)BT_*D_*2);
  u16* vtb   = (u16*)alloc((size_t)BT_*D_*2);
  u16* aob   = (u16*)alloc((size_t)BT_*D_*2);
  u16* midb  = (u16*)alloc((size_t)BT_*HF_*2);
  u16* qkvt  = (u16*)alloc((size_t)L_*3*D_*D_*2);
  u16* wot   = (u16*)alloc((size_t)L_*D_*D_*2);
  u16* w1t   = (u16*)alloc((size_t)L_*HF_*D_*2);
  u16* w2t   = (u16*)alloc((size_t)L_*D_*HF_*2);
  u16* headt = (u16*)alloc((size_t)V_*D_*2);

  const dim3 blk(256);
  // weight transposes: dst[n][k] = src[k][n], coalesced both sides
  wtrans_kernel<<<dim3(D_/32, D_/32, L_), blk, 0, stream>>>(wq, qkvt,           D_, D_, (size_t)D_*D_, (size_t)3*D_*D_);
  wtrans_kernel<<<dim3(D_/32, D_/32, L_), blk, 0, stream>>>(wk, qkvt + D_*D_,   D_, D_, (size_t)D_*D_, (size_t)3*D_*D_);
  wtrans_kernel<<<dim3(D_/32, D_/32, L_), blk, 0, stream>>>(wv, qkvt + 2*D_*D_, D_, D_, (size_t)D_*D_, (size_t)3*D_*D_);
  wtrans_kernel<<<dim3(D_/32, D_/32, L_), blk, 0, stream>>>(wo, wot,            D_, D_, (size_t)D_*D_, (size_t)D_*D_);
  wtrans_kernel<<<dim3(HF_/32, D_/32, L_), blk, 0, stream>>>(w1, w1t, D_, HF_, (size_t)D_*HF_, (size_t)HF_*D_);
  wtrans_kernel<<<dim3(D_/32, HF_/32, L_), blk, 0, stream>>>(w2, w2t, HF_, D_, (size_t)D_*HF_, (size_t)D_*HF_);
  wtrans_kernel<<<dim3(V_/32, D_/32, 1),  blk, 0, stream>>>(head, headt, D_, V_, 0, 0);

  embed_kernel<<<(BT_*D_ + 255)/256, blk, 0, stream>>>(x, emb, hbuf);

  for(int li=0; li<L_; li++){
    rms_kernel<<<BT_/4, blk, 0, stream>>>(hbuf, ln1 + li*D_, xn);
    gemm_kernel<3,D_><<<dim3(3*D_/128, BT_/128), blk, 0, stream>>>(
        xn, qkvt + (size_t)li*3*D_*D_, 3*D_, nullptr, nullptr, nullptr, qb, kb, vtb);
    flash_kernel<<<dim3(T_/64, B_*NH_), blk, 0, stream>>>(qb, kb, vtb, aob);
    gemm_kernel<2,D_><<<dim3(D_/128, BT_/128), blk, 0, stream>>>(
        aob, wot + (size_t)li*D_*D_, D_, nullptr, nullptr, hbuf, nullptr, nullptr, nullptr);
    rms_kernel<<<BT_/4, blk, 0, stream>>>(hbuf, ln2 + li*D_, xn);
    gemm_kernel<1,D_><<<dim3(HF_/128, BT_/128), blk, 0, stream>>>(
        xn, w1t + (size_t)li*HF_*D_, HF_, b1 + li*HF_, midb, nullptr, nullptr, nullptr, nullptr);
    gemm_kernel<2,HF_><<<dim3(D_/128, BT_/128), blk, 0, stream>>>(
        midb, w2t + (size_t)li*D_*HF_, D_, b2 + li*D_, nullptr, hbuf, nullptr, nullptr, nullptr);
    if(li == 2)
      copy_kernel<<<(BT_*D_ + 255)/256, blk, 0, stream>>>(hbuf, out + (size_t)BT_*V_, BT_*D_);
  }
  rms_kernel<<<BT_/4, blk, 0, stream>>>(hbuf, lnf, xn);
  gemm_kernel<0,D_><<<dim3(V_/128, BT_/128), blk, 0, stream>>>(
      xn, headt, V_, nullptr, nullptr, out, nullptr, nullptr, nullptr);
}

// Round 5
// 1374.118 us; speedup vs baseline: 1.9491x; 1.1152x over previous
//
#include <hip/hip_runtime.h>
#include <hip/hip_bf16.h>
#include <math.h>

#define L_  6
#define D_  384
#define NH_ 6
#define HD_ 64
#define HF_ 768
#define V_  4096
#define B_  4
#define T_  2048
#define BT_ (B_*T_)

typedef unsigned short u16;
typedef __attribute__((ext_vector_type(8))) short short8;
typedef __attribute__((ext_vector_type(4))) float f32x4;

__device__ __forceinline__ float bf2f(u16 u){
  union { unsigned int i; float f; } c; c.i = ((unsigned int)u)<<16; return c.f;
}
__device__ __forceinline__ u16 f2bf(float f){
  union { float f; unsigned int i; } c; c.f = f;
  unsigned int x = c.i;
  x += 0x7fffu + ((x>>16)&1u);
  return (u16)(x>>16);
}
__device__ __forceinline__ f32x4 mfma16(short8 a, short8 b, f32x4 c){
  return __builtin_amdgcn_mfma_f32_16x16x32_bf16(a,b,c,0,0,0);
}
// async global->LDS, 16B per lane, LDS dest = base + lane*16 (wave-uniform base)
#define GLD16(gp, lp) __builtin_amdgcn_global_load_lds( \
    (const __attribute__((address_space(1))) void*)(gp), \
    (__attribute__((address_space(3))) void*)(lp), 16, 0, 0)

// ---------------- embedding gather ----------------
__global__ void embed_kernel(const int* __restrict__ x, const float* __restrict__ emb,
                             float* __restrict__ h){
  const int idx = blockIdx.x*256 + threadIdx.x;
  if(idx >= BT_*D_) return;
  const int t = idx / D_;
  const int d = idx - t*D_;
  h[idx] = emb[(size_t)x[t]*D_ + d];
}

// ---- coalesced LDS-tiled weight transpose+cast: dst[b][n][k]=bf16(src[b][k][n])
__global__ __launch_bounds__(256) void wtrans_kernel(const float* __restrict__ src,
    u16* __restrict__ dst, int K, int N, size_t srcBatch, size_t dstBatch){
  __shared__ float tile[32][33];
  src += (size_t)blockIdx.z*srcBatch;
  dst += (size_t)blockIdx.z*dstBatch;
  const int tx = threadIdx.x&31, ty = threadIdx.x>>5;
  const int n0 = blockIdx.x*32, k0 = blockIdx.y*32;
  #pragma unroll
  for(int j=0;j<4;j++)
    tile[ty+j*8][tx] = src[(size_t)(k0+ty+j*8)*N + n0+tx];
  __syncthreads();
  #pragma unroll
  for(int j=0;j<4;j++)
    dst[(size_t)(n0+ty+j*8)*K + k0+tx] = f2bf(tile[tx][ty+j*8]);
}

// ---------------- rmsnorm: one wave per row of 384 ----------------
__global__ __launch_bounds__(256) void rms_kernel(const float* __restrict__ h,
                                                  const float* __restrict__ w,
                                                  u16* __restrict__ out){
  const int wave = threadIdx.x>>6, lane = threadIdx.x&63;
  const size_t row = (size_t)blockIdx.x*4 + wave;
  const float* hr = h + row*D_;
  float v[6]; float ss = 0.f;
  #pragma unroll
  for(int i=0;i<6;i++){ v[i] = hr[lane + i*64]; ss += v[i]*v[i]; }
  #pragma unroll
  for(int o=1;o<64;o<<=1) ss += __shfl_xor(ss, o);
  const float rn = rsqrtf(ss*(1.f/D_) + 1e-6f);
  u16* orow = out + row*D_;
  #pragma unroll
  for(int i=0;i<6;i++) orow[lane+i*64] = f2bf(v[i]*rn*w[lane+i*64]);
}

// ---------------- f32 -> f32 copy (mid output) ----------------
__global__ void copy_kernel(const float* __restrict__ src, float* __restrict__ dst, int n){
  const int i = blockIdx.x*256 + threadIdx.x;
  if(i < n) dst[i] = src[i];
}

// ---------------- MFMA GEMM: C[M,N] = A[M,K] @ Wt[N,K]^T ----------------
// BM=128 rows/block, BN in {128,64}. BK=64, global_load_lds staging into
// XOR-swizzled LDS. BN=128: 4 waves as 2x2 of 64x64. BN=64: 4 waves stacked
// in M, each 32x64. MODE: 0=f32 out, 1=bias+gelu bf16, 2=f32 resid +=,
// 3=QKV split (v transposed to [B,NH,HD,T]).
template<int MODE, int K, int BN>
__global__ __launch_bounds__(256) void gemm_kernel(
    const u16* __restrict__ A, const u16* __restrict__ Wt, int N,
    const float* __restrict__ bias, u16* __restrict__ out, float* __restrict__ fout,
    u16* __restrict__ qo, u16* __restrict__ ko, u16* __restrict__ vo)
{
  __shared__ u16 As[128*64];
  __shared__ u16 Bs[BN*64];
  const int w = threadIdx.x>>6, lane = threadIdx.x&63;
  const int l16 = lane&15, quad = lane>>4;
  const int r0 = blockIdx.y*128, n0 = blockIdx.x*BN;
  const int mst = lane>>3;                 // row within 1KB wave-chunk (8 rows)
  const int cst = (lane&7) ^ (lane>>3);    // swizzled 16B-chunk index

  constexpr int MI = (BN==128) ? 4 : 2;
  const int wrow = (BN==128) ? (w&1)*64 : w*32;   // wave row base in tile
  const int wcol = (BN==128) ? (w>>1)*64 : 0;     // wave col base in tile

  f32x4 acc[MI][4];
  #pragma unroll
  for(int mi=0;mi<MI;mi++)
    #pragma unroll
    for(int ni=0;ni<4;ni++){ acc[mi][ni][0]=0.f; acc[mi][ni][1]=0.f; acc[mi][ni][2]=0.f; acc[mi][ni][3]=0.f; }

  for(int k0=0;k0<K;k0+=64){
    __syncthreads();
    #pragma unroll
    for(int i=0;i<4;i++){
      const int m = (w*4+i)*8 + mst;       // 0..127
      GLD16(A + (size_t)(r0+m)*K + k0 + cst*8, As + (size_t)(w*4+i)*512);
    }
    if constexpr(BN==128){
      #pragma unroll
      for(int i=0;i<4;i++){
        const int n = (w*4+i)*8 + mst;
        GLD16(Wt + (size_t)(n0+n)*K + k0 + cst*8, Bs + (size_t)(w*4+i)*512);
      }
    } else {
      #pragma unroll
      for(int i=0;i<2;i++){
        const int n = (w*2+i)*8 + mst;     // 0..63
        GLD16(Wt + (size_t)(n0+n)*K + k0 + cst*8, Bs + (size_t)(w*2+i)*512);
      }
    }
    asm volatile("s_waitcnt vmcnt(0)" ::: "memory");
    __syncthreads();
    #pragma unroll
    for(int ks=0;ks<2;ks++){
      short8 av[MI], bv[4];
      #pragma unroll
      for(int mi=0;mi<MI;mi++){
        const int m = wrow + mi*16 + l16;
        av[mi] = *(const short8*)&As[m*64 + (((ks*4+quad)^(l16&7))*8)];
      }
      #pragma unroll
      for(int ni=0;ni<4;ni++){
        const int n = wcol + ni*16 + l16;
        bv[ni] = *(const short8*)&Bs[n*64 + (((ks*4+quad)^(l16&7))*8)];
      }
      #pragma unroll
      for(int mi=0;mi<MI;mi++)
        #pragma unroll
        for(int ni=0;ni<4;ni++)
          acc[mi][ni] = mfma16(av[mi], bv[ni], acc[mi][ni]);
    }
  }

  #pragma unroll
  for(int mi=0;mi<MI;mi++){
    #pragma unroll
    for(int ni=0;ni<4;ni++){
      const int col = n0 + wcol + ni*16 + l16;
      #pragma unroll
      for(int r=0;r<4;r++){
        const int row = r0 + wrow + mi*16 + quad*4 + r;
        float v = acc[mi][ni][r];
        if(MODE==0){
          fout[(size_t)row*N + col] = v;
        } else if(MODE==1){
          v += bias[col];
          v = 0.5f*v*(1.f + erff(v*0.70710678118f));
          out[(size_t)row*N + col] = f2bf(v);
        } else if(MODE==2){
          if(bias) v += bias[col];
          fout[(size_t)row*N + col] += v;
        } else {
          if(col < D_)        qo[(size_t)row*D_ + col]      = f2bf(v);
          else if(col < 2*D_) ko[(size_t)row*D_ + (col-D_)] = f2bf(v);
          else {
            const int cv = col - 2*D_;
            const int hh = cv>>6, dd = cv&63;
            const int bb = row>>11, tt = row&(T_-1);
            vo[(((size_t)(bb*NH_+hh))*HD_ + dd)*T_ + tt] = f2bf(v);
          }
        }
      }
    }
  }
}

// ---------------- causal flash attention ----------------
// grid (T/64, B*NH), 4 waves, 16 q rows/wave, 128-k tiles staged per block.
// qt reversed so heaviest blocks dispatch first.
__global__ __launch_bounds__(256) void flash_kernel(const u16* __restrict__ q,
    const u16* __restrict__ k, const u16* __restrict__ vt, u16* __restrict__ ao){
  __shared__ u16 Ks[128*64];                 // [k][d], row 64 u16 (8 chunks)
  __shared__ u16 Vs[64*128];                 // [d][k], row 128 u16 (16 chunks)
  __shared__ __align__(16) u16 Pb[4][16][136];
  const int w = threadIdx.x>>6, lane = threadIdx.x&63;
  const int l16 = lane&15, quad = lane>>4;
  const int bh = blockIdx.y, b = bh/NH_, h = bh - b*NH_;
  const int qt = (gridDim.x-1) - blockIdx.x;
  const int qw = qt*64 + w*16;

  const u16* qp = q + ((size_t)(b*T_ + qw + l16))*D_ + h*HD_ + quad*8;
  short8 qf0 = *(const short8*)(qp);
  short8 qf1 = *(const short8*)(qp + 32);

  const u16* kbase = k + (size_t)(b*T_)*D_ + h*HD_;
  const u16* vbase = vt + (size_t)(b*NH_ + h)*HD_*T_;

  float m[4], l[4];
  f32x4 o[4];
  #pragma unroll
  for(int r=0;r<4;r++){ m[r] = -1e30f; l[r] = 0.f; }
  #pragma unroll
  for(int c=0;c<4;c++){ o[c][0]=0.f; o[c][1]=0.f; o[c][2]=0.f; o[c][3]=0.f; }

  const int nkt = qt/2 + 1;     // causal: 128-k tiles covering k <= qt*64+63
  for(int kt=0; kt<nkt; kt++){
    const int kb = kt*128;
    __syncthreads();
    // stage K rows kb..kb+127 (swizzled: global chunk g at pos g^(row&7))
    #pragma unroll
    for(int i=0;i<4;i++){
      const int rr = (w*4+i)*8 + (lane>>3);
      const int gc = (lane&7) ^ (lane>>3);
      GLD16(kbase + (size_t)(kb + rr)*D_ + gc*8, Ks + (size_t)(w*4+i)*512);
    }
    // stage V^T rows d=0..63, cols kb..kb+127 (chunk g at pos g^(d&15))
    #pragma unroll
    for(int i=0;i<4;i++){
      const int dd = (w*4+i)*4 + (lane>>4);
      const int gc = (lane&15) ^ (dd&15);
      GLD16(vbase + (size_t)dd*T_ + kb + gc*8, Vs + (size_t)(w*4+i)*512);
    }
    asm volatile("s_waitcnt vmcnt(0)" ::: "memory");
    __syncthreads();

    float s[8][4];
    #pragma unroll
    for(int c=0;c<8;c++){
      const int krow = c*16 + l16;
      short8 kf0 = *(const short8*)&Ks[krow*64 + ((quad^(l16&7))*8)];
      short8 kf1 = *(const short8*)&Ks[krow*64 + (((4+quad)^(l16&7))*8)];
      f32x4 sa = {0.f,0.f,0.f,0.f};
      sa = mfma16(qf0, kf0, sa);
      sa = mfma16(qf1, kf1, sa);
      #pragma unroll
      for(int r=0;r<4;r++) s[c][r] = sa[r]*0.125f;
    }
    if(kt == nkt-1){
      #pragma unroll
      for(int c=0;c<8;c++){
        const int kpos = kb + c*16 + l16;
        #pragma unroll
        for(int r=0;r<4;r++)
          if(kpos > qw + quad*4 + r) s[c][r] = -1e30f;
      }
    }
    #pragma unroll
    for(int r=0;r<4;r++){
      float tm = s[0][r];
      #pragma unroll
      for(int c=1;c<8;c++) tm = fmaxf(tm, s[c][r]);
      tm = fmaxf(tm, __shfl_xor(tm,1));
      tm = fmaxf(tm, __shfl_xor(tm,2));
      tm = fmaxf(tm, __shfl_xor(tm,4));
      tm = fmaxf(tm, __shfl_xor(tm,8));
      const float mn = fmaxf(m[r], tm);
      const float al = __expf(m[r] - mn);
      float rs = 0.f;
      #pragma unroll
      for(int c=0;c<8;c++){
        const float p = __expf(s[c][r] - mn);
        rs += p;
        Pb[w][quad*4 + r][c*16 + l16] = f2bf(p);
      }
      rs += __shfl_xor(rs,1); rs += __shfl_xor(rs,2);
      rs += __shfl_xor(rs,4); rs += __shfl_xor(rs,8);
      l[r] = l[r]*al + rs;
      m[r] = mn;
      #pragma unroll
      for(int c=0;c<4;c++) o[c][r] *= al;
    }
    #pragma unroll
    for(int kk=0;kk<4;kk++){
      short8 pf = *(const short8*)&Pb[w][l16][kk*32 + quad*8];
      #pragma unroll
      for(int c=0;c<4;c++){
        const int dd = c*16 + l16;
        short8 vf = *(const short8*)&Vs[dd*128 + (((kk*4+quad)^(dd&15))*8)];
        o[c] = mfma16(pf, vf, o[c]);
      }
    }
  }
  #pragma unroll
  for(int c=0;c<4;c++){
    #pragma unroll
    for(int r=0;r<4;r++){
      const size_t row = (size_t)(b*T_ + qw + quad*4 + r);
      ao[row*D_ + h*HD_ + c*16 + l16] = f2bf(o[c][r] / l[r]);
    }
  }
}

extern "C" void kernel_launch(void* const* d_in, const int* in_sizes, int n_in,
                              void* d_out, int out_size, void* d_ws, size_t ws_size,
                              hipStream_t stream) {
  const int*   x    = (const int*)d_in[0];
  const float* emb  = (const float*)d_in[1];
  const float* wq   = (const float*)d_in[2];
  const float* wk   = (const float*)d_in[3];
  const float* wv   = (const float*)d_in[4];
  const float* wo   = (const float*)d_in[5];
  const float* ln1  = (const float*)d_in[6];
  const float* ln2  = (const float*)d_in[7];
  const float* w1   = (const float*)d_in[8];
  const float* b1   = (const float*)d_in[9];
  const float* w2   = (const float*)d_in[10];
  const float* b2   = (const float*)d_in[11];
  const float* lnf  = (const float*)d_in[12];
  const float* head = (const float*)d_in[13];
  float* out = (float*)d_out;

  char* ws = (char*)d_ws; size_t off = 0;
  auto alloc = [&](size_t bytes)->void* {
    void* p = ws + off; off += (bytes + 255) & ~(size_t)255; return p;
  };
  float* hbuf  = (float*)alloc((size_t)BT_*D_*4);
  u16* xn    = (u16*)alloc((size_t)BT_*D_*2);
  u16* qb    = (u16*)alloc((size_t)BT_*D_*2);
  u16* kb    = (u16*)alloc((size_t)BT_*D_*2);
  u16* vtb   = (u16*)alloc((size_t)BT_*D_*2);
  u16* aob   = (u16*)alloc((size_t)BT_*D_*2);
  u16* midb  = (u16*)alloc((size_t)BT_*HF_*2);
  u16* qkvt  = (u16*)alloc((size_t)L_*3*D_*D_*2);
  u16* wot   = (u16*)alloc((size_t)L_*D_*D_*2);
  u16* w1t   = (u16*)alloc((size_t)L_*HF_*D_*2);
  u16* w2t   = (u16*)alloc((size_t)L_*D_*HF_*2);
  u16* headt = (u16*)alloc((size_t)V_*D_*2);

  const dim3 blk(256);
  // weight transposes: dst[n][k] = src[k][n], coalesced both sides
  wtrans_kernel<<<dim3(D_/32, D_/32, L_), blk, 0, stream>>>(wq, qkvt,           D_, D_, (size_t)D_*D_, (size_t)3*D_*D_);
  wtrans_kernel<<<dim3(D_/32, D_/32, L_), blk, 0, stream>>>(wk, qkvt + D_*D_,   D_, D_, (size_t)D_*D_, (size_t)3*D_*D_);
  wtrans_kernel<<<dim3(D_/32, D_/32, L_), blk, 0, stream>>>(wv, qkvt + 2*D_*D_, D_, D_, (size_t)D_*D_, (size_t)3*D_*D_);
  wtrans_kernel<<<dim3(D_/32, D_/32, L_), blk, 0, stream>>>(wo, wot,            D_, D_, (size_t)D_*D_, (size_t)D_*D_);
  wtrans_kernel<<<dim3(HF_/32, D_/32, L_), blk, 0, stream>>>(w1, w1t, D_, HF_, (size_t)D_*HF_, (size_t)HF_*D_);
  wtrans_kernel<<<dim3(D_/32, HF_/32, L_), blk, 0, stream>>>(w2, w2t, HF_, D_, (size_t)D_*HF_, (size_t)D_*HF_);
  wtrans_kernel<<<dim3(V_/32, D_/32, 1),  blk, 0, stream>>>(head, headt, D_, V_, 0, 0);

  embed_kernel<<<(BT_*D_ + 255)/256, blk, 0, stream>>>(x, emb, hbuf);

  for(int li=0; li<L_; li++){
    rms_kernel<<<BT_/4, blk, 0, stream>>>(hbuf, ln1 + li*D_, xn);
    gemm_kernel<3,D_,128><<<dim3(3*D_/128, BT_/128), blk, 0, stream>>>(
        xn, qkvt + (size_t)li*3*D_*D_, 3*D_, nullptr, nullptr, nullptr, qb, kb, vtb);
    flash_kernel<<<dim3(T_/64, B_*NH_), blk, 0, stream>>>(qb, kb, vtb, aob);
    gemm_kernel<2,D_,64><<<dim3(D_/64, BT_/128), blk, 0, stream>>>(
        aob, wot + (size_t)li*D_*D_, D_, nullptr, nullptr, hbuf, nullptr, nullptr, nullptr);
    rms_kernel<<<BT_/4, blk, 0, stream>>>(hbuf, ln2 + li*D_, xn);
    gemm_kernel<1,D_,128><<<dim3(HF_/128, BT_/128), blk, 0, stream>>>(
        xn, w1t + (size_t)li*HF_*D_, HF_, b1 + li*HF_, midb, nullptr, nullptr, nullptr, nullptr);
    gemm_kernel<2,HF_,64><<<dim3(D_/64, BT_/128), blk, 0, stream>>>(
        midb, w2t + (size_t)li*D_*HF_, D_, b2 + li*D_, nullptr, hbuf, nullptr, nullptr, nullptr);
    if(li == 2)
      copy_kernel<<<(BT_*D_ + 255)/256, blk, 0, stream>>>(hbuf, out + (size_t)BT_*V_, BT_*D_);
  }
  rms_kernel<<<BT_/4, blk, 0, stream>>>(hbuf, lnf, xn);
  gemm_kernel<0,D_,128><<<dim3(V_/128, BT_/128), blk, 0, stream>>>(
      xn, headt, V_, nullptr, nullptr, out, nullptr, nullptr, nullptr);
}